// Round 4
// baseline (384.316 us; speedup 1.0000x reference)
//
#include <hip/hip_runtime.h>

#define TOPK 500
#define NCLS 80
#define NPOS 196   // 14*14
#define NLEV 5
#define OUT_B_OFF 0
#define OUT_C_OFF 2000
#define OUT_R_OFF 42000

typedef float nfloat4 __attribute__((ext_vector_type(4)));

// ---------------- workspace layout (bytes) ----------------
#define WS_HIST    0          // int hist0[256]  (pass-0, global atomics)
#define WS_TOP     4096       // int topIdx[512]
#define WS_SCORES  40960      // float scores[N] (~786 KB)
#define WS_FP8     (1u << 20) // fp8 feats, 5.59 MB
#define FEAT_PX    21824      // 16384+4096+1024+256+64
#define FP8_BYTES  ((size_t)FEAT_PX * 256)

// ---- fp8 e4m3fn helpers (manual, flush-subnormal, clamp-448) ----
__device__ inline unsigned f2fp8(float f) {
    unsigned u = __float_as_uint(f);
    unsigned s = (u >> 24) & 0x80u;
    unsigned au = u & 0x7FFFFFFFu;
    if (au < 0x3C800000u) return s;                    // |v| < 2^-6 -> 0
    unsigned r = au + 0x7FFFFu + ((au >> 20) & 1u);    // RNE at bit 20
    if (r >= 0x43E00000u) return s | 0x7Eu;            // clamp to 448
    unsigned e = r >> 23;                              // biased, 121..135
    return s | ((e - 120u) << 3) | ((r >> 20) & 7u);
}
__device__ inline float fp8dec(unsigned b) {
    unsigned b7 = b & 0x7Fu;
    unsigned fb = ((b & 0x80u) << 24) | (((b7 >> 3) + 120u) << 23) | ((b7 & 7u) << 20);
    return b7 < 8u ? 0.0f : __uint_as_float(fb);
}

__global__ void k_init(int* hist) {
    int t = threadIdx.x;
    if (t < 256) hist[t] = 0;
}

// fused: blocks [0,SC) compute scores + pass-0 hist; blocks [SC,..) convert feats->fp8
#define SC_BLOCKS 768
__global__ __launch_bounds__(256) void k_prep(
    const float* __restrict__ cls, float* __restrict__ scores, int* __restrict__ hist, int N,
    const float* __restrict__ p3, const float* __restrict__ p4,
    const float* __restrict__ p5, const float* __restrict__ p6,
    const float* __restrict__ p7, unsigned* __restrict__ dst) {
    int b = blockIdx.x;
    if (b < SC_BLOCKS) {
        __shared__ int lh[256];
        int t = threadIdx.x;
        lh[t] = 0;
        __syncthreads();
        int i = b * 256 + t;
        if (i < N) {
            const float4* p = (const float4*)(cls + (size_t)i * NCLS);
            float m = -1e30f;
#pragma unroll
            for (int k = 0; k < NCLS / 4; ++k) {
                float4 v = p[k];
                m = fmaxf(m, fmaxf(fmaxf(v.x, v.y), fmaxf(v.z, v.w)));
            }
            scores[i] = m;
            atomicAdd(&lh[__float_as_uint(m) >> 24], 1);
        }
        __syncthreads();
        int c = lh[t];
        if (c) atomicAdd(&hist[t], c);
    } else {
        int i = (b - SC_BLOCKS) * 256 + threadIdx.x;  // float4 chunk, total 1,396,736
        const int n0 = 1048576, n1 = 262144, n2 = 65536, n3 = 16384;
        const float* src; int off;
        if (i < n0)               { src = p3; off = i; }
        else if (i < n0+n1)       { src = p4; off = i - n0; }
        else if (i < n0+n1+n2)    { src = p5; off = i - n0 - n1; }
        else if (i < n0+n1+n2+n3) { src = p6; off = i - n0 - n1 - n2; }
        else                      { src = p7; off = i - n0 - n1 - n2 - n3; }
        float4 v = ((const float4*)src)[off];
        unsigned r = f2fp8(v.x) | (f2fp8(v.y) << 8) | (f2fp8(v.z) << 16) | (f2fp8(v.w) << 24);
        dst[i] = r;
    }
}

// single-block select: radix passes 1-3 (LDS hist), collect, bitonic sort,
// write topIdx + gather boxes/classes into out.
__global__ __launch_bounds__(1024) void k_select(
    const float* __restrict__ scores, int N, const int* __restrict__ hist0,
    const float* __restrict__ boxes, const float* __restrict__ cls,
    int* __restrict__ topIdx, float* __restrict__ out) {
    __shared__ int lh[256];
    __shared__ unsigned sPrefix;
    __shared__ int sK;
    __shared__ int nGt, nEq;
    __shared__ int gtIdx[512];
    __shared__ int eqIdx[1024];
    __shared__ unsigned long long key[1024];
    int tid = threadIdx.x;

    // pass 0 pick from global hist
    if (tid == 0) {
        int k = TOPK, chosen = 0, cum = 0;
        for (int b2 = 255; b2 >= 0; --b2) {
            int hb = hist0[b2];
            if (cum + hb >= k) { chosen = b2; break; }
            cum += hb;
        }
        sK = k - cum;
        sPrefix = ((unsigned)chosen) << 24;
        nGt = 0; nEq = 0;
    }
    __syncthreads();

    // passes 1..3
    for (int pass = 1; pass < 4; ++pass) {
        if (tid < 256) lh[tid] = 0;
        __syncthreads();
        unsigned prefix = sPrefix;
        int shift = 24 - 8 * pass;
        unsigned mask = 0xFFFFFFFFu << (32 - 8 * pass);
        for (int i = tid; i < N; i += 1024) {
            unsigned bits = __float_as_uint(scores[i]);
            if ((bits & mask) == prefix)
                atomicAdd(&lh[(bits >> shift) & 0xFF], 1);
        }
        __syncthreads();
        if (tid == 0) {
            int k = sK, chosen = 0, cum = 0;
            for (int b2 = 255; b2 >= 0; --b2) {
                int hb = lh[b2];
                if (cum + hb >= k) { chosen = b2; break; }
                cum += hb;
            }
            sK = k - cum;
            sPrefix |= ((unsigned)chosen) << shift;
        }
        __syncthreads();
    }

    // collect
    unsigned T = sPrefix;
    for (int i = tid; i < N; i += 1024) {
        unsigned bits = __float_as_uint(scores[i]);
        if (bits > T) {
            int p = atomicAdd(&nGt, 1);
            if (p < 512) gtIdx[p] = i;
        } else if (bits == T) {
            int p = atomicAdd(&nEq, 1);
            if (p < 1024) eqIdx[p] = i;
        }
    }
    __syncthreads();

    int cntGt = min(nGt, 512);
    int eqTake = min(min(nEq, 1024), 1024 - cntGt);
    int total = cntGt + eqTake;
    unsigned long long kk = 0ull;
    if (tid < cntGt) {
        int idx = gtIdx[tid];
        kk = ((unsigned long long)__float_as_uint(scores[idx]) << 32) | (unsigned)(~idx);
    } else if (tid < total) {
        int idx = eqIdx[tid - cntGt];
        kk = ((unsigned long long)T << 32) | (unsigned)(~idx);
    }
    key[tid] = kk;
    __syncthreads();
    for (int k = 2; k <= 1024; k <<= 1) {
        for (int j = k >> 1; j > 0; j >>= 1) {
            int ixj = tid ^ j;
            if (ixj > tid) {
                unsigned long long a = key[tid], b2 = key[ixj];
                bool desc = ((tid & k) == 0);
                if (desc ? (a < b2) : (a > b2)) { key[tid] = b2; key[ixj] = a; }
            }
            __syncthreads();
        }
    }
    if (tid < TOPK) topIdx[tid] = (int)(~(unsigned)(key[tid] & 0xFFFFFFFFull));
    __syncthreads();

    // gather boxes (500x4) + classes (500x80) into out
    for (int e = tid; e < TOPK * (NCLS + 4); e += 1024) {
        int j = e / (NCLS + 4);
        int k = e - j * (NCLS + 4);
        int idx = (int)(~(unsigned)(key[j] & 0xFFFFFFFFull));
        if (k < 4) out[OUT_B_OFF + j * 4 + k] = boxes[(size_t)idx * 4 + k];
        else       out[OUT_C_OFF + j * NCLS + (k - 4)] = cls[(size_t)idx * NCLS + (k - 4)];
    }
}

// ROI: 4 positions / 256-thread block; 64 lanes/position, 4 channels/lane.
template <int USE_FP8>
__global__ __launch_bounds__(256) void k_roi(
    const float* __restrict__ boxes, const int* __restrict__ topIdx,
    const int* __restrict__ ishape, const unsigned char* __restrict__ feat,
    const float* __restrict__ f0, const float* __restrict__ f1,
    const float* __restrict__ f2, const float* __restrict__ f3,
    const float* __restrict__ f4,
    float* __restrict__ out) {
    const int lvlOff[5] = {0, 16384, 20480, 21504, 21760};
    int P  = blockIdx.x * 4 + (threadIdx.x >> 6);
    int c4 = threadIdx.x & 63;
    int j = P / NPOS;
    int pos = P - j * NPOS;
    int y = pos / 14, x = pos - (pos / 14) * 14;
    int idx = topIdx[j];
    float bx1 = boxes[idx * 4 + 0];
    float by1 = boxes[idx * 4 + 1];
    float bx2 = boxes[idx * 4 + 2];
    float by2 = boxes[idx * 4 + 3];
    float hf = (float)ishape[1];
    float wf = (float)ishape[2];
    float ny1 = by1 / hf, nx1 = bx1 / wf, ny2 = by2 / hf, nx2 = bx2 / wf;
    float ty = (float)y / 13.0f;
    float tx = (float)x / 13.0f;
    const float* fm[5] = {f0, f1, f2, f3, f4};
    float* o = out + OUT_R_OFF + (size_t)P * (NLEV * 256);
#pragma unroll
    for (int l = 0; l < NLEV; ++l) {
        int H = 128 >> l;
        float Hm1 = (float)(H - 1);
        float ys = (ny1 + ty * (ny2 - ny1)) * Hm1;
        float xs = (nx1 + tx * (nx2 - nx1)) * Hm1;
        float y0f = floorf(ys), x0f = floorf(xs);
        float wy = ys - y0f, wx = xs - x0f;
        int y0  = min(max((int)y0f, 0), H - 1);
        int y1c = min(max((int)y0f + 1, 0), H - 1);
        int x0  = min(max((int)x0f, 0), H - 1);
        int x1c = min(max((int)x0f + 1, 0), H - 1);
        bool valid = (ys >= 0.0f) && (ys <= Hm1) && (xs >= 0.0f) && (xs <= Hm1);
        float w00 = (1.0f - wy) * (1.0f - wx);
        float w01 = (1.0f - wy) * wx;
        float w10 = wy * (1.0f - wx);
        float w11 = wy * wx;
        nfloat4 res;
        if (USE_FP8) {
            const unsigned char* base = feat + ((size_t)lvlOff[l] << 8) + c4 * 4;
            unsigned a = *(const unsigned*)(base + ((size_t)(y0  * H + x0 ) << 8));
            unsigned b = *(const unsigned*)(base + ((size_t)(y0  * H + x1c) << 8));
            unsigned c = *(const unsigned*)(base + ((size_t)(y1c * H + x0 ) << 8));
            unsigned d = *(const unsigned*)(base + ((size_t)(y1c * H + x1c) << 8));
#pragma unroll
            for (int q = 0; q < 4; ++q) {
                int sh = 8 * q;
                res[q] = w00 * fp8dec((a >> sh) & 0xFF) + w01 * fp8dec((b >> sh) & 0xFF)
                       + w10 * fp8dec((c >> sh) & 0xFF) + w11 * fp8dec((d >> sh) & 0xFF);
            }
        } else {
            const float* f = fm[l];
            float4 a = ((const float4*)(f + ((size_t)(y0  * H + x0 ) << 8)))[c4];
            float4 b = ((const float4*)(f + ((size_t)(y0  * H + x1c) << 8)))[c4];
            float4 c = ((const float4*)(f + ((size_t)(y1c * H + x0 ) << 8)))[c4];
            float4 d = ((const float4*)(f + ((size_t)(y1c * H + x1c) << 8)))[c4];
            res.x = w00 * a.x + w01 * b.x + w10 * c.x + w11 * d.x;
            res.y = w00 * a.y + w01 * b.y + w10 * c.y + w11 * d.y;
            res.z = w00 * a.z + w01 * b.z + w10 * c.z + w11 * d.z;
            res.w = w00 * a.w + w01 * b.w + w10 * c.w + w11 * d.w;
        }
        if (!valid) { res.x = 0.f; res.y = 0.f; res.z = 0.f; res.w = 0.f; }
        __builtin_nontemporal_store(res, (nfloat4*)(o + l * 256) + c4);
    }
}

extern "C" void kernel_launch(void* const* d_in, const int* in_sizes, int n_in,
                              void* d_out, int out_size, void* d_ws, size_t ws_size,
                              hipStream_t stream) {
    const int*   ishape = (const int*)d_in[0];
    const float* boxes  = (const float*)d_in[1];
    const float* cls    = (const float*)d_in[2];
    const float* p3     = (const float*)d_in[3];
    const float* p4     = (const float*)d_in[4];
    const float* p5     = (const float*)d_in[5];
    const float* p6     = (const float*)d_in[6];
    const float* p7     = (const float*)d_in[7];
    float* out = (float*)d_out;

    int N = in_sizes[2] / NCLS;   // 196416

    char* ws = (char*)d_ws;
    int*      hist   = (int*)(ws + WS_HIST);
    int*      topIdx = (int*)(ws + WS_TOP);
    float*    scores = (float*)(ws + WS_SCORES);
    unsigned* feat   = (unsigned*)(ws + WS_FP8);

    bool useFp8 = ws_size >= (size_t)WS_FP8 + FP8_BYTES;

    hipLaunchKernelGGL(k_init, dim3(1), dim3(256), 0, stream, hist);
    if (useFp8) {
        hipLaunchKernelGGL(k_prep, dim3(SC_BLOCKS + 5456), dim3(256), 0, stream,
                           cls, scores, hist, N, p3, p4, p5, p6, p7, feat);
    } else {
        hipLaunchKernelGGL(k_prep, dim3(SC_BLOCKS), dim3(256), 0, stream,
                           cls, scores, hist, N, p3, p4, p5, p6, p7, feat);
    }
    hipLaunchKernelGGL(k_select, dim3(1), dim3(1024), 0, stream,
                       scores, N, hist, boxes, cls, topIdx, out);
    if (useFp8)
        hipLaunchKernelGGL((k_roi<1>), dim3(TOPK * NPOS / 4), dim3(256), 0, stream,
                           boxes, topIdx, ishape, (const unsigned char*)feat, p3, p4, p5, p6, p7, out);
    else
        hipLaunchKernelGGL((k_roi<0>), dim3(TOPK * NPOS / 4), dim3(256), 0, stream,
                           boxes, topIdx, ishape, (const unsigned char*)feat, p3, p4, p5, p6, p7, out);
}

// Round 5
// 243.988 us; speedup vs baseline: 1.5751x; 1.5751x over previous
//
#include <hip/hip_runtime.h>

#define TOPK 500
#define NCLS 80
#define NPOS 196   // 14*14
#define NLEV 5
#define OUT_B_OFF 0
#define OUT_C_OFF 2000
#define OUT_R_OFF 42000

typedef float nfloat4 __attribute__((ext_vector_type(4)));

// ---------------- workspace layout (bytes) ----------------
#define WS_STATE   0          // int state[16]  5:nGt 6:nEq
#define WS_HIST    64         // int hist[4][256]
#define WS_GT      8192       // int gtIdx[512]
#define WS_EQ      12288      // int eqIdx[1024]
#define WS_TOP     16384      // int topIdx[512]
#define WS_SCORES  40960      // float scores[N] (~786 KB)
#define WS_BF16    (1u << 20) // bf16 feats, 10.7 MB
#define FEAT_PX    21824      // 16384+4096+1024+256+64
#define BF16_BYTES ((size_t)FEAT_PX * 256 * 2)

__device__ inline unsigned short f2bf(float f) {
    unsigned u = __float_as_uint(f);
    return (unsigned short)((u + 0x7FFFu + ((u >> 16) & 1u)) >> 16);
}

__global__ void k_init(int* state, int* hist) {
    int t = threadIdx.x;
    if (t < 1024) hist[t] = 0;
    if (t < 16) state[t] = 0;
}

// fused: blocks [0,SC) compute scores + pass-0 hist; blocks [SC,..) convert feats->bf16
#define SC_BLOCKS 768
__global__ __launch_bounds__(256) void k_prep(
    const float* __restrict__ cls, float* __restrict__ scores, int* __restrict__ hist, int N,
    const float* __restrict__ p3, const float* __restrict__ p4,
    const float* __restrict__ p5, const float* __restrict__ p6,
    const float* __restrict__ p7, ushort* __restrict__ dst) {
    int b = blockIdx.x;
    if (b < SC_BLOCKS) {
        __shared__ int lh[256];
        int t = threadIdx.x;
        lh[t] = 0;
        __syncthreads();
        int i = b * 256 + t;
        if (i < N) {
            const float4* p = (const float4*)(cls + (size_t)i * NCLS);
            float m = -1e30f;
#pragma unroll
            for (int k = 0; k < NCLS / 4; ++k) {
                float4 v = p[k];
                m = fmaxf(m, fmaxf(fmaxf(v.x, v.y), fmaxf(v.z, v.w)));
            }
            scores[i] = m;
            atomicAdd(&lh[__float_as_uint(m) >> 24], 1);
        }
        __syncthreads();
        int c = lh[t];
        if (c) atomicAdd(&hist[t], c);
    } else {
        int i = (b - SC_BLOCKS) * 256 + threadIdx.x;  // float4 chunk, total 1,396,736
        const int n0 = 1048576, n1 = 262144, n2 = 65536, n3 = 16384;
        const float* src; int off;
        if (i < n0)               { src = p3; off = i; }
        else if (i < n0+n1)       { src = p4; off = i - n0; }
        else if (i < n0+n1+n2)    { src = p5; off = i - n0 - n1; }
        else if (i < n0+n1+n2+n3) { src = p6; off = i - n0 - n1 - n2; }
        else                      { src = p7; off = i - n0 - n1 - n2 - n3; }
        float4 v = ((const float4*)src)[off];
        ushort4 r;
        r.x = f2bf(v.x); r.y = f2bf(v.y); r.z = f2bf(v.z); r.w = f2bf(v.w);
        ((ushort4*)dst)[i] = r;
    }
}

// replay radix picks from completed histograms (scores are positive floats)
__device__ inline unsigned replay_prefix(const int* hist, int passes) {
    int k = TOPK;
    unsigned prefix = 0;
    for (int p = 0; p < passes; ++p) {
        const int* h = hist + (p << 8);
        int cum = 0, chosen = 0;
        for (int b = 255; b >= 0; --b) {
            int hb = h[b];
            if (cum + hb >= k) { chosen = b; break; }
            cum += hb;
        }
        k -= cum;
        prefix |= ((unsigned)chosen) << (24 - 8 * p);
    }
    return prefix;
}

__global__ __launch_bounds__(256) void k_hist(
    const float* __restrict__ scores, int N,
    int* __restrict__ hist, int pass) {
    __shared__ int lh[256];
    __shared__ unsigned s_prefix;
    int t = threadIdx.x;
    lh[t] = 0;
    if (t == 0) s_prefix = replay_prefix(hist, pass);
    __syncthreads();
    unsigned prefix = s_prefix;
    int shift = 24 - 8 * pass;
    unsigned mask = 0xFFFFFFFFu << (32 - 8 * pass);
    for (int i = blockIdx.x * blockDim.x + t; i < N; i += gridDim.x * blockDim.x) {
        unsigned bits = __float_as_uint(scores[i]);
        if ((bits & mask) == prefix)
            atomicAdd(&lh[(bits >> shift) & 0xFF], 1);
    }
    __syncthreads();
    int c = lh[t];
    if (c) atomicAdd(&hist[pass * 256 + t], c);
}

__global__ __launch_bounds__(256) void k_collect(
    const float* __restrict__ scores, int N, const int* __restrict__ hist,
    int* state, int* gtIdx, int* eqIdx) {
    __shared__ unsigned sT;
    if (threadIdx.x == 0) sT = replay_prefix(hist, 4);
    __syncthreads();
    unsigned T = sT;
    int i = blockIdx.x * blockDim.x + threadIdx.x;
    if (i >= N) return;
    unsigned bits = __float_as_uint(scores[i]);
    if (bits > T) {
        int p = atomicAdd(&state[5], 1);
        if (p < 512) gtIdx[p] = i;
    } else if (bits == T) {
        int p = atomicAdd(&state[6], 1);
        if (p < 1024) eqIdx[p] = i;
    }
}

// single-block: rank candidates by counting (no bitonic), write topIdx,
// gather boxes (500x4) + classes (500x80) into out.
__global__ __launch_bounds__(1024) void k_sel(
    const float* __restrict__ scores, const int* __restrict__ hist,
    const int* __restrict__ state,
    const int* __restrict__ gtIdx, const int* __restrict__ eqIdx,
    const float* __restrict__ boxes, const float* __restrict__ cls,
    int* __restrict__ topIdx, float* __restrict__ out) {
    __shared__ unsigned long long key[1024];
    __shared__ int ordTop[TOPK];
    __shared__ unsigned sT;
    int tid = threadIdx.x;
    if (tid == 0) sT = replay_prefix(hist, 4);
    __syncthreads();
    unsigned T = sT;
    int cntGt  = min(state[5], 512);
    int eqTake = min(min(state[6], 1024), 1024 - cntGt);
    int total  = cntGt + eqTake;
    unsigned long long me = 0ull;
    int myIdx = -1;
    if (tid < cntGt) {
        myIdx = gtIdx[tid];
        me = ((unsigned long long)__float_as_uint(scores[myIdx]) << 32) | (unsigned)(~myIdx);
    } else if (tid < total) {
        myIdx = eqIdx[tid - cntGt];
        me = ((unsigned long long)T << 32) | (unsigned)(~myIdx);
    }
    key[tid] = me;
    __syncthreads();
    if (tid < total) {
        int r = 0;
        for (int j = 0; j < 1024; ++j) r += (key[j] > me);
        if (r < TOPK) { topIdx[r] = myIdx; ordTop[r] = myIdx; }
    }
    __syncthreads();
    for (int e = tid; e < TOPK * (NCLS + 4); e += 1024) {
        int j = e / (NCLS + 4);
        int k = e - j * (NCLS + 4);
        int idx = ordTop[j];
        if (k < 4) out[OUT_B_OFF + j * 4 + k] = boxes[(size_t)idx * 4 + k];
        else       out[OUT_C_OFF + j * NCLS + (k - 4)] = cls[(size_t)idx * NCLS + (k - 4)];
    }
}

// ROI: 4 positions / 256-thread block; 64 lanes/position, 4 channels/lane. bf16 feats.
template <int USE_BF16>
__global__ __launch_bounds__(256) void k_roi(
    const float* __restrict__ boxes, const int* __restrict__ topIdx,
    const int* __restrict__ ishape, const ushort* __restrict__ feat,
    const float* __restrict__ f0, const float* __restrict__ f1,
    const float* __restrict__ f2, const float* __restrict__ f3,
    const float* __restrict__ f4,
    float* __restrict__ out) {
    const int lvlOff[5] = {0, 16384, 20480, 21504, 21760};
    // bijective XCD-chunked swizzle (m204): consecutive positions -> same XCD L2
    int nwg = gridDim.x;
    int q = nwg >> 3, r = nwg & 7;
    int orig = blockIdx.x;
    int xcd = orig & 7, i8 = orig >> 3;
    int wg = (xcd < r ? xcd * (q + 1) : r * (q + 1) + (xcd - r) * q) + i8;
    int P  = wg * 4 + (threadIdx.x >> 6);
    int c4 = threadIdx.x & 63;
    int j = P / NPOS;
    int pos = P - j * NPOS;
    int y = pos / 14, x = pos - (pos / 14) * 14;
    int idx = topIdx[j];
    float bx1 = boxes[idx * 4 + 0];
    float by1 = boxes[idx * 4 + 1];
    float bx2 = boxes[idx * 4 + 2];
    float by2 = boxes[idx * 4 + 3];
    float hf = (float)ishape[1];
    float wf = (float)ishape[2];
    float ny1 = by1 / hf, nx1 = bx1 / wf, ny2 = by2 / hf, nx2 = bx2 / wf;
    float ty = (float)y / 13.0f;
    float tx = (float)x / 13.0f;
    const float* fm[5] = {f0, f1, f2, f3, f4};
    float* o = out + OUT_R_OFF + (size_t)P * (NLEV * 256);
#pragma unroll
    for (int l = 0; l < NLEV; ++l) {
        int H = 128 >> l;
        float Hm1 = (float)(H - 1);
        float ys = (ny1 + ty * (ny2 - ny1)) * Hm1;
        float xs = (nx1 + tx * (nx2 - nx1)) * Hm1;
        float y0f = floorf(ys), x0f = floorf(xs);
        float wy = ys - y0f, wx = xs - x0f;
        int y0  = min(max((int)y0f, 0), H - 1);
        int y1c = min(max((int)y0f + 1, 0), H - 1);
        int x0  = min(max((int)x0f, 0), H - 1);
        int x1c = min(max((int)x0f + 1, 0), H - 1);
        bool valid = (ys >= 0.0f) && (ys <= Hm1) && (xs >= 0.0f) && (xs <= Hm1);
        float w00 = (1.0f - wy) * (1.0f - wx);
        float w01 = (1.0f - wy) * wx;
        float w10 = wy * (1.0f - wx);
        float w11 = wy * wx;
        nfloat4 res;
        if (USE_BF16) {
            const ushort* base = feat + ((size_t)lvlOff[l] << 8);
            ushort4 a = ((const ushort4*)(base + ((size_t)(y0  * H + x0 ) << 8)))[c4];
            ushort4 b = ((const ushort4*)(base + ((size_t)(y0  * H + x1c) << 8)))[c4];
            ushort4 c = ((const ushort4*)(base + ((size_t)(y1c * H + x0 ) << 8)))[c4];
            ushort4 d = ((const ushort4*)(base + ((size_t)(y1c * H + x1c) << 8)))[c4];
#define BF(u) __uint_as_float(((unsigned)(u)) << 16)
            res.x = w00 * BF(a.x) + w01 * BF(b.x) + w10 * BF(c.x) + w11 * BF(d.x);
            res.y = w00 * BF(a.y) + w01 * BF(b.y) + w10 * BF(c.y) + w11 * BF(d.y);
            res.z = w00 * BF(a.z) + w01 * BF(b.z) + w10 * BF(c.z) + w11 * BF(d.z);
            res.w = w00 * BF(a.w) + w01 * BF(b.w) + w10 * BF(c.w) + w11 * BF(d.w);
#undef BF
        } else {
            const float* f = fm[l];
            float4 a = ((const float4*)(f + ((size_t)(y0  * H + x0 ) << 8)))[c4];
            float4 b = ((const float4*)(f + ((size_t)(y0  * H + x1c) << 8)))[c4];
            float4 c = ((const float4*)(f + ((size_t)(y1c * H + x0 ) << 8)))[c4];
            float4 d = ((const float4*)(f + ((size_t)(y1c * H + x1c) << 8)))[c4];
            res.x = w00 * a.x + w01 * b.x + w10 * c.x + w11 * d.x;
            res.y = w00 * a.y + w01 * b.y + w10 * c.y + w11 * d.y;
            res.z = w00 * a.z + w01 * b.z + w10 * c.z + w11 * d.z;
            res.w = w00 * a.w + w01 * b.w + w10 * c.w + w11 * d.w;
        }
        if (!valid) { res.x = 0.f; res.y = 0.f; res.z = 0.f; res.w = 0.f; }
        __builtin_nontemporal_store(res, (nfloat4*)(o + l * 256) + c4);
    }
}

extern "C" void kernel_launch(void* const* d_in, const int* in_sizes, int n_in,
                              void* d_out, int out_size, void* d_ws, size_t ws_size,
                              hipStream_t stream) {
    const int*   ishape = (const int*)d_in[0];
    const float* boxes  = (const float*)d_in[1];
    const float* cls    = (const float*)d_in[2];
    const float* p3     = (const float*)d_in[3];
    const float* p4     = (const float*)d_in[4];
    const float* p5     = (const float*)d_in[5];
    const float* p6     = (const float*)d_in[6];
    const float* p7     = (const float*)d_in[7];
    float* out = (float*)d_out;

    int N = in_sizes[2] / NCLS;   // 196416

    char* ws = (char*)d_ws;
    int*    state  = (int*)(ws + WS_STATE);
    int*    hist   = (int*)(ws + WS_HIST);
    int*    gtIdx  = (int*)(ws + WS_GT);
    int*    eqIdx  = (int*)(ws + WS_EQ);
    int*    topIdx = (int*)(ws + WS_TOP);
    float*  scores = (float*)(ws + WS_SCORES);
    ushort* feat   = (ushort*)(ws + WS_BF16);

    bool useBf16 = ws_size >= (size_t)WS_BF16 + BF16_BYTES;

    hipLaunchKernelGGL(k_init, dim3(1), dim3(1024), 0, stream, state, hist);
    hipLaunchKernelGGL(k_prep, dim3(useBf16 ? SC_BLOCKS + 5456 : SC_BLOCKS), dim3(256), 0, stream,
                       cls, scores, hist, N, p3, p4, p5, p6, p7, feat);
    for (int pass = 1; pass < 4; ++pass)
        hipLaunchKernelGGL(k_hist, dim3(256), dim3(256), 0, stream, scores, N, hist, pass);
    hipLaunchKernelGGL(k_collect, dim3((N + 255) / 256), dim3(256), 0, stream,
                       scores, N, hist, state, gtIdx, eqIdx);
    hipLaunchKernelGGL(k_sel, dim3(1), dim3(1024), 0, stream,
                       scores, hist, state, gtIdx, eqIdx, boxes, cls, topIdx, out);
    if (useBf16)
        hipLaunchKernelGGL((k_roi<1>), dim3(TOPK * NPOS / 4), dim3(256), 0, stream,
                           boxes, topIdx, ishape, feat, p3, p4, p5, p6, p7, out);
    else
        hipLaunchKernelGGL((k_roi<0>), dim3(TOPK * NPOS / 4), dim3(256), 0, stream,
                           boxes, topIdx, ishape, feat, p3, p4, p5, p6, p7, out);
}